// Round 1
// baseline (1211.547 us; speedup 1.0000x reference)
//
#include <hip/hip_runtime.h>

#define N_NODES 50000
#define N_EDGES 800000
#define B_GRAPH 256
#define IN_DIM  128
#define HID     64   // d = 64 for every layer; 2d = 128

// -------------------- initial latent: p = relu(z @ lin_w + lin_b) --------------------
__global__ __launch_bounds__(256) void k_linz(const float* __restrict__ z,
                                              const float* __restrict__ w,
                                              const float* __restrict__ b,
                                              float* __restrict__ p) {
    int idx = blockIdx.x * blockDim.x + threadIdx.x;   // B_GRAPH*HID = 16384
    if (idx >= B_GRAPH * HID) return;
    int row = idx >> 6, c = idx & 63;
    float acc = b[c];
    const float* zr = z + row * IN_DIM;
#pragma unroll 8
    for (int k = 0; k < IN_DIM; ++k) acc = fmaf(zr[k], w[k * HID + c], acc);
    p[idx] = fmaxf(acc, 0.f);
}

// -------------------- x0[n] = p[batch[n]] --------------------
__global__ __launch_bounds__(256) void k_gather(const float* __restrict__ p,
                                                const int* __restrict__ batch,
                                                float* __restrict__ x0) {
    int idx = blockIdx.x * blockDim.x + threadIdx.x;
    if (idx >= N_NODES * 64) return;
    int n = idx >> 6, c = idx & 63;
    x0[idx] = p[batch[n] * 64 + c];
}

// -------------------- CSR build --------------------
__global__ __launch_bounds__(256) void k_count(const int* __restrict__ dst,
                                               int* __restrict__ counts) {
    int e = blockIdx.x * blockDim.x + threadIdx.x;
    if (e < N_EDGES) atomicAdd(&counts[dst[e]], 1);
}

// single-block exclusive scan; counts may alias cursor (reads complete before writes)
__global__ __launch_bounds__(1024) void k_scan(const int* counts,
                                               int* rowstart,
                                               int* cursor) {
    __shared__ int buf[1024];
    __shared__ int carry;
    int tid = threadIdx.x;
    if (tid == 0) carry = 0;
    __syncthreads();
    for (int base = 0; base < N_NODES; base += 1024) {
        int i = base + tid;
        int v = (i < N_NODES) ? counts[i] : 0;
        buf[tid] = v;
        __syncthreads();
        for (int off = 1; off < 1024; off <<= 1) {
            int t = (tid >= off) ? buf[tid - off] : 0;
            __syncthreads();
            buf[tid] += t;
            __syncthreads();
        }
        int excl = buf[tid] - v + carry;
        if (i < N_NODES) { rowstart[i] = excl; cursor[i] = excl; }
        __syncthreads();
        if (tid == 0) carry += buf[1023];
        __syncthreads();
    }
    if (tid == 0) rowstart[N_NODES] = carry;
}

__global__ __launch_bounds__(256) void k_scatter(const int* __restrict__ src,
                                                 const int* __restrict__ dst,
                                                 int* __restrict__ cursor,
                                                 int* __restrict__ csr_src,
                                                 int* __restrict__ csr_eid) {
    int e = blockIdx.x * blockDim.x + threadIdx.x;
    if (e >= N_EDGES) return;
    int d = dst[e];
    int pos = atomicAdd(&cursor[d], 1);
    csr_src[pos] = src[e];
    csr_eid[pos] = e;
}

// -------------------- edge pass: one wave per node, lane = channel --------------------
// agg[n] = sum(msg*exp(msg)) / (sum(exp(msg)) + 1e-16) + x[n]
// msg = relu(x[src] + edge_attr @ ew + eb) + 1e-7
// (no max-shift: softmax is shift-invariant; msg is O(10) so exp() is safe in fp32)
__global__ __launch_bounds__(256) void k_edge(const float* __restrict__ x,
                                              const int* __restrict__ rowstart,
                                              const int* __restrict__ csr_src,
                                              const int* __restrict__ csr_eid,
                                              const float* __restrict__ edge_attr,
                                              const float* __restrict__ ew,
                                              const float* __restrict__ eb,
                                              float* __restrict__ agg) {
    __shared__ float s_ew[16 * 64];
    __shared__ float s_eb[64];
    int tid = threadIdx.x;
    for (int i = tid; i < 16 * 64; i += 256) s_ew[i] = ew[i];
    if (tid < 64) s_eb[tid] = eb[tid];
    __syncthreads();
    int lane = tid & 63;
    int n = blockIdx.x * 4 + (tid >> 6);
    if (n >= N_NODES) return;
    int beg = rowstart[n], end = rowstart[n + 1];
    float xres = x[n * 64 + lane];
    float num = 0.f, den = 0.f;
    for (int i = beg; i < end; ++i) {
        int s   = csr_src[i];
        int eid = csr_eid[i];
        float ea = (lane < 16) ? edge_attr[eid * 16 + lane] : 0.f;
        float xs = x[s * 64 + lane];
        float el = s_eb[lane];
#pragma unroll
        for (int k = 0; k < 16; ++k)
            el = fmaf(__shfl(ea, k, 64), s_ew[k * 64 + lane], el);
        float m  = fmaxf(xs + el, 0.f) + 1e-7f;
        float ee = __expf(m);
        num = fmaf(m, ee, num);
        den += ee;
    }
    agg[n * 64 + lane] = num / (den + 1e-16f) + xres;
}

// -------------------- t = agg @ w1 + b1 ; accumulate per-channel sum/sumsq --------------------
__global__ __launch_bounds__(256) void k_mlp1(const float* __restrict__ agg,
                                              const float* __restrict__ w1,
                                              const float* __restrict__ b1,
                                              float* __restrict__ tbuf,
                                              float* __restrict__ s1) {
    __shared__ float s_w[64 * 128];
    __shared__ float red[256];
    int tid = threadIdx.x;
    for (int i = tid; i < 64 * 128; i += 256) s_w[i] = w1[i];
    __syncthreads();
    int c = tid & 127, half = tid >> 7;
    float bc = b1[c];
    float lsum = 0.f, lsq = 0.f;
    for (int n = blockIdx.x * 2 + half; n < N_NODES; n += gridDim.x * 2) {
        const float* ar = agg + n * 64;
        float acc = bc;
#pragma unroll 16
        for (int k = 0; k < 64; ++k) acc = fmaf(ar[k], s_w[k * 128 + c], acc);
        tbuf[n * 128 + c] = acc;
        lsum += acc;
        lsq = fmaf(acc, acc, lsq);
    }
    red[tid] = lsum;
    __syncthreads();
    if (half == 0) atomicAdd(&s1[c], red[c] + red[c + 128]);
    __syncthreads();
    red[tid] = lsq;
    __syncthreads();
    if (half == 0) atomicAdd(&s1[128 + c], red[c] + red[c + 128]);
}

// -------------------- y = relu(bn(t)) @ w2 + b2 ; accumulate y stats --------------------
__global__ __launch_bounds__(256) void k_mlp2(const float* __restrict__ tbuf,
                                              const float* __restrict__ w2,
                                              const float* __restrict__ b2,
                                              const float* __restrict__ s1,
                                              const float* __restrict__ bng,
                                              const float* __restrict__ bnb,
                                              float* __restrict__ ybuf,
                                              float* __restrict__ s2) {
    __shared__ float s_w[128 * 64];
    __shared__ float hbuf[4 * 128];
    __shared__ float red[256];
    int tid = threadIdx.x;
    for (int i = tid; i < 128 * 64; i += 256) s_w[i] = w2[i];
    int cc = tid & 127;   // phase-A channel (fixed per thread)
    float mu  = s1[cc] * (1.f / N_NODES);
    float var = s1[128 + cc] * (1.f / N_NODES) - mu * mu;
    float inv = rsqrtf(var + 1e-5f);
    float sA = inv * bng[cc];
    float sB = bnb[cc] - mu * sA;      // bn(t) = t*sA + sB
    int c = tid & 63, slot = tid >> 6; // phase-B mapping
    float b2c = b2[c];
    float lsum = 0.f, lsq = 0.f;
    __syncthreads();
    for (int base = blockIdx.x * 4; base < N_NODES; base += gridDim.x * 4) {
        int r0 = tid >> 7;             // 0..1 ; handles rows r0 and r0+2
        int n0 = base + r0, n1 = base + r0 + 2;
        hbuf[r0 * 128 + cc]       = (n0 < N_NODES) ? fmaxf(fmaf(tbuf[n0 * 128 + cc], sA, sB), 0.f) : 0.f;
        hbuf[(r0 + 2) * 128 + cc] = (n1 < N_NODES) ? fmaxf(fmaf(tbuf[n1 * 128 + cc], sA, sB), 0.f) : 0.f;
        __syncthreads();
        int n = base + slot;
        if (n < N_NODES) {
            float acc = b2c;
#pragma unroll 16
            for (int k = 0; k < 128; ++k) acc = fmaf(hbuf[slot * 128 + k], s_w[k * 64 + c], acc);
            ybuf[n * 64 + c] = acc;
            lsum += acc;
            lsq = fmaf(acc, acc, lsq);
        }
        __syncthreads();
    }
    red[tid] = lsum;
    __syncthreads();
    if (slot == 0) atomicAdd(&s2[c], red[c] + red[c + 64] + red[c + 128] + red[c + 192]);
    __syncthreads();
    red[tid] = lsq;
    __syncthreads();
    if (slot == 0) atomicAdd(&s2[64 + c], red[c] + red[c + 64] + red[c + 128] + red[c + 192]);
}

// -------------------- outer BN (+ optional relu) --------------------
__global__ __launch_bounds__(256) void k_bn2(const float* __restrict__ y,
                                             const float* __restrict__ s2,
                                             const float* __restrict__ g,
                                             const float* __restrict__ b,
                                             float* __restrict__ xout,
                                             int relu) {
    int idx = blockIdx.x * blockDim.x + threadIdx.x;
    if (idx >= N_NODES * 64) return;
    int c = idx & 63;
    float mu  = s2[c] * (1.f / N_NODES);
    float var = s2[64 + c] * (1.f / N_NODES) - mu * mu;
    float inv = rsqrtf(var + 1e-5f);
    float v = (y[idx] - mu) * inv * g[c] + b[c];
    if (relu) v = fmaxf(v, 0.f);
    xout[idx] = v;
}

extern "C" void kernel_launch(void* const* d_in, const int* in_sizes, int n_in,
                              void* d_out, int out_size, void* d_ws, size_t ws_size,
                              hipStream_t stream) {
    const float* z     = (const float*)d_in[0];
    const int*   batch = (const int*)  d_in[1];
    const int*   eidx  = (const int*)  d_in[2];
    const float* eattr = (const float*)d_in[3];
    const float* lin_w = (const float*)d_in[4];
    const float* lin_b = (const float*)d_in[5];
    const int* src = eidx;
    const int* dst = eidx + N_EDGES;

    char* ws = (char*)d_ws;
    size_t off = 0;
    auto alloc = [&](size_t bytes) -> void* {
        void* p = ws + off;
        off = (off + bytes + 255) & ~(size_t)255;
        return p;
    };
    float* p        = (float*)alloc((size_t)B_GRAPH * HID * 4);
    float* x0       = (float*)alloc((size_t)N_NODES * 64 * 4);
    float* x1       = (float*)alloc((size_t)N_NODES * 64 * 4);
    float* agg      = (float*)alloc((size_t)N_NODES * 64 * 4);   // also reused as ybuf
    float* tbuf     = (float*)alloc((size_t)N_NODES * 128 * 4);
    int*   rowstart = (int*)  alloc((size_t)(N_NODES + 1) * 4);
    int*   cursor   = (int*)  alloc((size_t)(N_NODES + 1) * 4);  // doubles as counts
    int*   csr_src  = (int*)  alloc((size_t)N_EDGES * 4);
    int*   csr_eid  = (int*)  alloc((size_t)N_EDGES * 4);
    float* stats    = (float*)alloc((size_t)3 * 384 * 4);

    hipMemsetAsync(cursor, 0, (size_t)(N_NODES + 1) * 4, stream);
    hipMemsetAsync(stats,  0, (size_t)3 * 384 * 4, stream);

    k_linz  <<<(B_GRAPH * HID + 255) / 256, 256, 0, stream>>>(z, lin_w, lin_b, p);
    k_gather<<<(N_NODES * 64 + 255) / 256, 256, 0, stream>>>(p, batch, x0);
    k_count <<<(N_EDGES + 255) / 256, 256, 0, stream>>>(dst, cursor);
    k_scan  <<<1, 1024, 0, stream>>>(cursor, rowstart, cursor);
    k_scatter<<<(N_EDGES + 255) / 256, 256, 0, stream>>>(src, dst, cursor, csr_src, csr_eid);

    for (int l = 0; l < 3; ++l) {
        const float* ew  = (const float*)d_in[6 + l * 10 + 0];
        const float* eb  = (const float*)d_in[6 + l * 10 + 1];
        const float* w1  = (const float*)d_in[6 + l * 10 + 2];
        const float* b1  = (const float*)d_in[6 + l * 10 + 3];
        const float* bng = (const float*)d_in[6 + l * 10 + 4];
        const float* bnb = (const float*)d_in[6 + l * 10 + 5];
        const float* w2  = (const float*)d_in[6 + l * 10 + 6];
        const float* b2  = (const float*)d_in[6 + l * 10 + 7];
        const float* ng  = (const float*)d_in[6 + l * 10 + 8];
        const float* nb  = (const float*)d_in[6 + l * 10 + 9];

        float* xin  = (l == 0) ? x0 : ((l == 1) ? x1 : x0);
        float* xout = (l == 0) ? x1 : ((l == 1) ? x0 : (float*)d_out);
        float* s1 = stats + l * 384;
        float* s2 = s1 + 256;

        k_edge<<<(N_NODES + 3) / 4, 256, 0, stream>>>(xin, rowstart, csr_src, csr_eid,
                                                      eattr, ew, eb, agg);
        k_mlp1<<<256, 256, 0, stream>>>(agg, w1, b1, tbuf, s1);
        k_mlp2<<<256, 256, 0, stream>>>(tbuf, w2, b2, s1, bng, bnb, agg, s2);
        k_bn2 <<<(N_NODES * 64 + 255) / 256, 256, 0, stream>>>(agg, s2, ng, nb, xout,
                                                               (l < 2) ? 1 : 0);
    }
}

// Round 2
// 1027.365 us; speedup vs baseline: 1.1793x; 1.1793x over previous
//
#include <hip/hip_runtime.h>

#define N_NODES 50000
#define N_EDGES 800000
#define B_GRAPH 256
#define IN_DIM  128
#define HID     64   // d = 64 for every layer; 2d = 128

// -------------------- initial latent: p = relu(z @ lin_w + lin_b) --------------------
__global__ __launch_bounds__(256) void k_linz(const float* __restrict__ z,
                                              const float* __restrict__ w,
                                              const float* __restrict__ b,
                                              float* __restrict__ p) {
    int idx = blockIdx.x * blockDim.x + threadIdx.x;   // B_GRAPH*HID = 16384
    if (idx >= B_GRAPH * HID) return;
    int row = idx >> 6, c = idx & 63;
    float acc = b[c];
    const float* zr = z + row * IN_DIM;
#pragma unroll 8
    for (int k = 0; k < IN_DIM; ++k) acc = fmaf(zr[k], w[k * HID + c], acc);
    p[idx] = fmaxf(acc, 0.f);
}

// -------------------- x0[n] = p[batch[n]] (float4) --------------------
__global__ __launch_bounds__(256) void k_gather(const float* __restrict__ p,
                                                const int* __restrict__ batch,
                                                float* __restrict__ x0) {
    int idx = blockIdx.x * blockDim.x + threadIdx.x;   // N*16 float4s
    if (idx >= N_NODES * 16) return;
    int n = idx >> 4, q = idx & 15;
    ((float4*)x0)[idx] = ((const float4*)(p + batch[n] * 64))[q];
}

// -------------------- CSR build --------------------
__global__ __launch_bounds__(256) void k_count(const int* __restrict__ dst,
                                               int* __restrict__ counts) {
    int e = blockIdx.x * blockDim.x + threadIdx.x;
    if (e < N_EDGES) atomicAdd(&counts[dst[e]], 1);
}

// shfl-based scan: 3 barriers per 1024-chunk (counts may alias cursor)
__global__ __launch_bounds__(1024) void k_scan(const int* counts,
                                               int* rowstart,
                                               int* cursor) {
    __shared__ int wsum[16];
    int tid = threadIdx.x, lane = tid & 63, w = tid >> 6;
    int carry = 0;
    for (int base = 0; base < N_NODES; base += 1024) {
        int i = base + tid;
        int v = (i < N_NODES) ? counts[i] : 0;
        int s = v;
#pragma unroll
        for (int off = 1; off < 64; off <<= 1) {
            int t = __shfl_up(s, off, 64);
            if (lane >= off) s += t;
        }
        if (lane == 63) wsum[w] = s;
        __syncthreads();
        if (w == 0) {
            int ws = (lane < 16) ? wsum[lane] : 0;
#pragma unroll
            for (int off = 1; off < 16; off <<= 1) {
                int t = __shfl_up(ws, off, 64);
                if (lane >= off) ws += t;
            }
            if (lane < 16) wsum[lane] = ws;
        }
        __syncthreads();
        int wbase = (w == 0) ? 0 : wsum[w - 1];
        int excl = carry + wbase + s - v;
        if (i < N_NODES) { rowstart[i] = excl; cursor[i] = excl; }
        carry += wsum[15];
        __syncthreads();
    }
    if (tid == 0) rowstart[N_NODES] = carry;
}

__global__ __launch_bounds__(256) void k_scatter(const int* __restrict__ src,
                                                 const int* __restrict__ dst,
                                                 int* __restrict__ cursor,
                                                 int* __restrict__ csr_src,
                                                 int* __restrict__ csr_eid) {
    int e = blockIdx.x * blockDim.x + threadIdx.x;
    if (e >= N_EDGES) return;
    int d = dst[e];
    int pos = atomicAdd(&cursor[d], 1);
    csr_src[pos] = src[e];
    csr_eid[pos] = e;
}

// -------------------- edge pass: one wave per node, lane = channel --------------------
// 8-edge software pipeline: batch index loads, 8 gathers in flight, ew in registers.
__global__ __launch_bounds__(256) void k_edge(const float* __restrict__ x,
                                              const int* __restrict__ rowstart,
                                              const int* __restrict__ csr_src,
                                              const int* __restrict__ csr_eid,
                                              const float* __restrict__ edge_attr,
                                              const float* __restrict__ ew,
                                              const float* __restrict__ eb,
                                              float* __restrict__ agg) {
    int tid = threadIdx.x;
    int lane = tid & 63;
    int n = blockIdx.x * 4 + (tid >> 6);
    if (n >= N_NODES) return;
    float rw[16];
#pragma unroll
    for (int k = 0; k < 16; ++k) rw[k] = ew[k * 64 + lane];   // L1/L2-resident, 4KB total
    float ebl = eb[lane];
    int beg = rowstart[n], end = rowstart[n + 1];
    float xres = x[n * 64 + lane];
    float num = 0.f, den = 0.f;
    int i = beg;
    for (; i + 8 <= end; i += 8) {
        int sv = csr_src[i + (lane & 7)];
        int ev = csr_eid[i + (lane & 7)];
        float xs[8], ea[8];
#pragma unroll
        for (int j = 0; j < 8; ++j) {
            int s = __shfl(sv, j, 64);
            xs[j] = x[s * 64 + lane];
        }
#pragma unroll
        for (int j = 0; j < 8; ++j) {
            int eid = __shfl(ev, j, 64);
            ea[j] = (lane < 16) ? edge_attr[eid * 16 + lane] : 0.f;
        }
#pragma unroll
        for (int j = 0; j < 8; ++j) {
            float el = ebl;
#pragma unroll
            for (int k = 0; k < 16; ++k) el = fmaf(__shfl(ea[j], k, 64), rw[k], el);
            float m  = fmaxf(xs[j] + el, 0.f) + 1e-7f;
            float e2 = __expf(m);
            num = fmaf(m, e2, num);
            den += e2;
        }
    }
    for (; i < end; ++i) {
        int s   = csr_src[i];
        int eid = csr_eid[i];
        float xsv = x[s * 64 + lane];
        float eav = (lane < 16) ? edge_attr[eid * 16 + lane] : 0.f;
        float el = ebl;
#pragma unroll
        for (int k = 0; k < 16; ++k) el = fmaf(__shfl(eav, k, 64), rw[k], el);
        float m  = fmaxf(xsv + el, 0.f) + 1e-7f;
        float e2 = __expf(m);
        num = fmaf(m, e2, num);
        den += e2;
    }
    agg[n * 64 + lane] = num / (den + 1e-16f) + xres;
}

// -------------------- t = agg @ w1 + b1 ; accumulate per-channel sum/sumsq --------------------
__global__ __launch_bounds__(256) void k_mlp1(const float* __restrict__ agg,
                                              const float* __restrict__ w1,
                                              const float* __restrict__ b1,
                                              float* __restrict__ tbuf,
                                              float* __restrict__ s1) {
    __shared__ float s_w[64 * 128];
    __shared__ float red[256];
    int tid = threadIdx.x;
    for (int i = tid; i < 64 * 128 / 4; i += 256) ((float4*)s_w)[i] = ((const float4*)w1)[i];
    __syncthreads();
    int c = tid & 127, half = tid >> 7;
    float bc = b1[c];
    float lsum = 0.f, lsq = 0.f;
    for (int n = blockIdx.x * 2 + half; n < N_NODES; n += gridDim.x * 2) {
        const float* ar = agg + n * 64;
        float a0 = bc, a1 = 0.f;
#pragma unroll
        for (int k = 0; k < 64; k += 2) {
            a0 = fmaf(ar[k],     s_w[k * 128 + c],       a0);
            a1 = fmaf(ar[k + 1], s_w[(k + 1) * 128 + c], a1);
        }
        float acc = a0 + a1;
        tbuf[n * 128 + c] = acc;
        lsum += acc;
        lsq = fmaf(acc, acc, lsq);
    }
    red[tid] = lsum;
    __syncthreads();
    if (half == 0) atomicAdd(&s1[c], red[c] + red[c + 128]);
    __syncthreads();
    red[tid] = lsq;
    __syncthreads();
    if (half == 0) atomicAdd(&s1[128 + c], red[c] + red[c + 128]);
}

// -------------------- y = relu(bn(t)) @ w2 + b2 ; accumulate y stats --------------------
// one wave per node; lane = output channel; h-row in 2 regs/lane, readlane broadcast.
__global__ __launch_bounds__(256) void k_mlp2(const float* __restrict__ tbuf,
                                              const float* __restrict__ w2,
                                              const float* __restrict__ b2,
                                              const float* __restrict__ s1,
                                              const float* __restrict__ bng,
                                              const float* __restrict__ bnb,
                                              float* __restrict__ ybuf,
                                              float* __restrict__ s2) {
    __shared__ float s_w[128 * 64];
    __shared__ float red[4][64][2];
    int tid = threadIdx.x, lane = tid & 63, w = tid >> 6;
    for (int i = tid; i < 128 * 64 / 4; i += 256) ((float4*)s_w)[i] = ((const float4*)w2)[i];
    // per-lane BN coeffs for channels lane and lane+64
    float mu0 = s1[lane] * (1.f / N_NODES);
    float v0  = s1[128 + lane] * (1.f / N_NODES) - mu0 * mu0;
    float iA  = rsqrtf(v0 + 1e-5f) * bng[lane];
    float iB  = bnb[lane] - mu0 * iA;
    float mu1 = s1[lane + 64] * (1.f / N_NODES);
    float v1  = s1[128 + lane + 64] * (1.f / N_NODES) - mu1 * mu1;
    float jA  = rsqrtf(v1 + 1e-5f) * bng[lane + 64];
    float jB  = bnb[lane + 64] - mu1 * jA;
    float b2c = b2[lane];
    float lsum = 0.f, lsq = 0.f;
    __syncthreads();
    for (int n = blockIdx.x * 4 + w; n < N_NODES; n += gridDim.x * 4) {
        float t0 = tbuf[n * 128 + lane];
        float t1 = tbuf[n * 128 + 64 + lane];
        float h0 = fmaxf(fmaf(t0, iA, iB), 0.f);
        float h1 = fmaxf(fmaf(t1, jA, jB), 0.f);
        float a0 = b2c, a1 = 0.f, a2 = 0.f, a3 = 0.f;
#pragma unroll
        for (int k = 0; k < 64; k += 2) {
            a0 = fmaf(__shfl(h0, k,     64), s_w[k * 64 + lane],        a0);
            a1 = fmaf(__shfl(h0, k + 1, 64), s_w[(k + 1) * 64 + lane],  a1);
            a2 = fmaf(__shfl(h1, k,     64), s_w[(k + 64) * 64 + lane], a2);
            a3 = fmaf(__shfl(h1, k + 1, 64), s_w[(k + 65) * 64 + lane], a3);
        }
        float acc = (a0 + a1) + (a2 + a3);
        ybuf[n * 64 + lane] = acc;
        lsum += acc;
        lsq = fmaf(acc, acc, lsq);
    }
    red[w][lane][0] = lsum;
    red[w][lane][1] = lsq;
    __syncthreads();
    if (w == 0) {
        float s = red[0][lane][0] + red[1][lane][0] + red[2][lane][0] + red[3][lane][0];
        float q = red[0][lane][1] + red[1][lane][1] + red[2][lane][1] + red[3][lane][1];
        atomicAdd(&s2[lane], s);
        atomicAdd(&s2[64 + lane], q);
    }
}

// -------------------- outer BN (+ optional relu), float4 --------------------
__global__ __launch_bounds__(256) void k_bn2(const float* __restrict__ y,
                                             const float* __restrict__ s2,
                                             const float* __restrict__ g,
                                             const float* __restrict__ b,
                                             float* __restrict__ xout,
                                             int relu) {
    int idx = blockIdx.x * blockDim.x + threadIdx.x;   // N*16 float4s
    if (idx >= N_NODES * 16) return;
    int c0 = (idx & 15) * 4;
    float4 v = ((const float4*)y)[idx];
    float* vp = &v.x;
    float out[4];
#pragma unroll
    for (int j = 0; j < 4; ++j) {
        int c = c0 + j;
        float mu  = s2[c] * (1.f / N_NODES);
        float var = s2[64 + c] * (1.f / N_NODES) - mu * mu;
        float inv = rsqrtf(var + 1e-5f);
        float o = (vp[j] - mu) * inv * g[c] + b[c];
        out[j] = relu ? fmaxf(o, 0.f) : o;
    }
    ((float4*)xout)[idx] = make_float4(out[0], out[1], out[2], out[3]);
}

extern "C" void kernel_launch(void* const* d_in, const int* in_sizes, int n_in,
                              void* d_out, int out_size, void* d_ws, size_t ws_size,
                              hipStream_t stream) {
    const float* z     = (const float*)d_in[0];
    const int*   batch = (const int*)  d_in[1];
    const int*   eidx  = (const int*)  d_in[2];
    const float* eattr = (const float*)d_in[3];
    const float* lin_w = (const float*)d_in[4];
    const float* lin_b = (const float*)d_in[5];
    const int* src = eidx;
    const int* dst = eidx + N_EDGES;

    char* ws = (char*)d_ws;
    size_t off = 0;
    auto alloc = [&](size_t bytes) -> void* {
        void* p = ws + off;
        off = (off + bytes + 255) & ~(size_t)255;
        return p;
    };
    float* p        = (float*)alloc((size_t)B_GRAPH * HID * 4);
    float* x0       = (float*)alloc((size_t)N_NODES * 64 * 4);
    float* x1       = (float*)alloc((size_t)N_NODES * 64 * 4);
    float* agg      = (float*)alloc((size_t)N_NODES * 64 * 4);   // also reused as ybuf
    float* tbuf     = (float*)alloc((size_t)N_NODES * 128 * 4);
    int*   rowstart = (int*)  alloc((size_t)(N_NODES + 1) * 4);
    int*   cursor   = (int*)  alloc((size_t)(N_NODES + 1) * 4);  // doubles as counts
    int*   csr_src  = (int*)  alloc((size_t)N_EDGES * 4);
    int*   csr_eid  = (int*)  alloc((size_t)N_EDGES * 4);
    float* stats    = (float*)alloc((size_t)3 * 384 * 4);

    hipMemsetAsync(cursor, 0, (size_t)(N_NODES + 1) * 4, stream);
    hipMemsetAsync(stats,  0, (size_t)3 * 384 * 4, stream);

    k_linz  <<<(B_GRAPH * HID + 255) / 256, 256, 0, stream>>>(z, lin_w, lin_b, p);
    k_gather<<<(N_NODES * 16 + 255) / 256, 256, 0, stream>>>(p, batch, x0);
    k_count <<<(N_EDGES + 255) / 256, 256, 0, stream>>>(dst, cursor);
    k_scan  <<<1, 1024, 0, stream>>>(cursor, rowstart, cursor);
    k_scatter<<<(N_EDGES + 255) / 256, 256, 0, stream>>>(src, dst, cursor, csr_src, csr_eid);

    for (int l = 0; l < 3; ++l) {
        const float* ew  = (const float*)d_in[6 + l * 10 + 0];
        const float* eb  = (const float*)d_in[6 + l * 10 + 1];
        const float* w1  = (const float*)d_in[6 + l * 10 + 2];
        const float* b1  = (const float*)d_in[6 + l * 10 + 3];
        const float* bng = (const float*)d_in[6 + l * 10 + 4];
        const float* bnb = (const float*)d_in[6 + l * 10 + 5];
        const float* w2  = (const float*)d_in[6 + l * 10 + 6];
        const float* b2  = (const float*)d_in[6 + l * 10 + 7];
        const float* ng  = (const float*)d_in[6 + l * 10 + 8];
        const float* nb  = (const float*)d_in[6 + l * 10 + 9];

        float* xin  = (l == 0) ? x0 : ((l == 1) ? x1 : x0);
        float* xout = (l == 0) ? x1 : ((l == 1) ? x0 : (float*)d_out);
        float* s1 = stats + l * 384;
        float* s2 = s1 + 256;

        k_edge<<<(N_NODES + 3) / 4, 256, 0, stream>>>(xin, rowstart, csr_src, csr_eid,
                                                      eattr, ew, eb, agg);
        k_mlp1<<<512, 256, 0, stream>>>(agg, w1, b1, tbuf, s1);
        k_mlp2<<<512, 256, 0, stream>>>(tbuf, w2, b2, s1, bng, bnb, agg, s2);
        k_bn2 <<<(N_NODES * 16 + 255) / 256, 256, 0, stream>>>(agg, s2, ng, nb, xout,
                                                               (l < 2) ? 1 : 0);
    }
}

// Round 3
// 807.757 us; speedup vs baseline: 1.4999x; 1.2719x over previous
//
#include <hip/hip_runtime.h>
#include <hip/hip_fp16.h>

#define N_NODES 50000
#define N_EDGES 800000
#define B_GRAPH 256
#define IN_DIM  128
#define HID     64
#define NBLK_SCAN ((N_NODES + 1023) / 1024)   // 49

__device__ __forceinline__ float bcastf(float v, int l) {
    return __int_as_float(__builtin_amdgcn_readlane(__float_as_int(v), l));
}

// -------------------- initial latent: p = relu(z @ lin_w + lin_b) --------------------
__global__ __launch_bounds__(256) void k_linz(const float* __restrict__ z,
                                              const float* __restrict__ w,
                                              const float* __restrict__ b,
                                              float* __restrict__ p) {
    int idx = blockIdx.x * blockDim.x + threadIdx.x;
    if (idx >= B_GRAPH * HID) return;
    int row = idx >> 6, c = idx & 63;
    float acc = b[c];
    const float* zr = z + row * IN_DIM;
#pragma unroll 8
    for (int k = 0; k < IN_DIM; ++k) acc = fmaf(zr[k], w[k * HID + c], acc);
    p[idx] = fmaxf(acc, 0.f);
}

// -------------------- x0[n] = p[batch[n]] (float4) --------------------
__global__ __launch_bounds__(256) void k_gather(const float* __restrict__ p,
                                                const int* __restrict__ batch,
                                                float* __restrict__ x0) {
    int idx = blockIdx.x * blockDim.x + threadIdx.x;
    if (idx >= N_NODES * 16) return;
    int n = idx >> 4, q = idx & 15;
    ((float4*)x0)[idx] = ((const float4*)(p + batch[n] * 64))[q];
}

// -------------------- CSR build --------------------
__global__ __launch_bounds__(256) void k_count(const int* __restrict__ dst,
                                               int* __restrict__ counts) {
    int e = blockIdx.x * blockDim.x + threadIdx.x;
    if (e < N_EDGES) atomicAdd(&counts[dst[e]], 1);
}

// two-level scan: A) per-1024-block local excl scan + block totals
__global__ __launch_bounds__(1024) void k_scanA(const int* __restrict__ counts,
                                                int* __restrict__ rowstart,
                                                int* __restrict__ btot) {
    __shared__ int wsum[16];
    int tid = threadIdx.x, lane = tid & 63, w = tid >> 6;
    int i = blockIdx.x * 1024 + tid;
    int v = (i < N_NODES) ? counts[i] : 0;
    int s = v;
#pragma unroll
    for (int off = 1; off < 64; off <<= 1) {
        int t = __shfl_up(s, off, 64);
        if (lane >= off) s += t;
    }
    if (lane == 63) wsum[w] = s;
    __syncthreads();
    if (w == 0) {
        int ws = (lane < 16) ? wsum[lane] : 0;
#pragma unroll
        for (int off = 1; off < 16; off <<= 1) {
            int t = __shfl_up(ws, off, 64);
            if (lane >= off) ws += t;
        }
        if (lane < 16) wsum[lane] = ws;
    }
    __syncthreads();
    int wbase = (w == 0) ? 0 : wsum[w - 1];
    if (i < N_NODES) rowstart[i] = wbase + s - v;
    if (tid == 0) btot[blockIdx.x] = wsum[15];
}

// B) scan the 49 block totals (single wave)
__global__ __launch_bounds__(64) void k_scanB(const int* __restrict__ btot,
                                              int* __restrict__ boff) {
    int lane = threadIdx.x;
    int v = (lane < NBLK_SCAN) ? btot[lane] : 0;
    int s = v;
#pragma unroll
    for (int off = 1; off < 64; off <<= 1) {
        int t = __shfl_up(s, off, 64);
        if (lane >= off) s += t;
    }
    if (lane < NBLK_SCAN) boff[lane] = s - v;
    if (lane == 63) boff[NBLK_SCAN] = s;   // grand total
}

// C) add block offsets; produce cursor copy
__global__ __launch_bounds__(256) void k_scanC(int* __restrict__ rowstart,
                                               const int* __restrict__ boff,
                                               int* __restrict__ cursor) {
    int i = blockIdx.x * blockDim.x + threadIdx.x;
    if (i < N_NODES) {
        int r = rowstart[i] + boff[i >> 10];
        rowstart[i] = r;
        cursor[i] = r;
    } else if (i == N_NODES) {
        rowstart[N_NODES] = boff[NBLK_SCAN];
    }
}

__global__ __launch_bounds__(256) void k_scatter(const int* __restrict__ src,
                                                 const int* __restrict__ dst,
                                                 int* __restrict__ cursor,
                                                 int* __restrict__ csr_src,
                                                 int* __restrict__ csr_eid) {
    int e = blockIdx.x * blockDim.x + threadIdx.x;
    if (e >= N_EDGES) return;
    int d = dst[e];
    int pos = atomicAdd(&cursor[d], 1);
    csr_src[pos] = src[e];
    csr_eid[pos] = e;
}

// -------------------- permute edge_attr into CSR order (fp16) --------------------
__global__ __launch_bounds__(256) void k_permute(const float* __restrict__ ea,
                                                 const int* __restrict__ csr_eid,
                                                 __half* __restrict__ attr_p) {
    int idx = blockIdx.x * blockDim.x + threadIdx.x;   // E*16
    if (idx >= N_EDGES * 16) return;
    int i = idx >> 4, k = idx & 15;
    attr_p[idx] = __float2half(ea[csr_eid[i] * 16 + k]);
}

// -------------------- edge pass: one wave per node (grid-stride), lane = channel ----
// Input y is the PRE-BN previous-layer output; BN(+relu) applied on the fly via sA/sB.
// Predicated chunk-4: one coalesced attr load covers 4 edges x 16 attrs; readlane bcast.
__global__ __launch_bounds__(256) void k_edge(const float* __restrict__ y,
                                              const float* __restrict__ s2,
                                              const float* __restrict__ bg,
                                              const float* __restrict__ bb,
                                              float relu_neg,
                                              const int* __restrict__ rowstart,
                                              const int* __restrict__ csr_src,
                                              const __half* __restrict__ attr_p,
                                              const float* __restrict__ ew,
                                              const float* __restrict__ eb,
                                              float* __restrict__ agg) {
    int tid = threadIdx.x, lane = tid & 63;
    float rw[16];
#pragma unroll
    for (int k = 0; k < 16; ++k) rw[k] = ew[k * 64 + lane];
    float ebl = eb[lane];
    float sA = 1.f, sB = 0.f;
    if (s2) {
        float mu  = s2[lane] * (1.f / N_NODES);
        float var = s2[64 + lane] * (1.f / N_NODES) - mu * mu;
        sA = rsqrtf(var + 1e-5f) * bg[lane];
        sB = bb[lane] - mu * sA;
    }
    int wave = blockIdx.x * 4 + (tid >> 6);
    int nw = gridDim.x * 4;
    for (int n = wave; n < N_NODES; n += nw) {
        int beg = rowstart[n], end = rowstart[n + 1];
        float xr = fmaxf(fmaf(y[n * 64 + lane], sA, sB), relu_neg);
        float num = 0.f, den = 0.f;
        for (int i = beg; i < end; i += 4) {
            int lim = end - 1;
            int sv = csr_src[min(i + (lane & 3), lim)];
            float ea = __half2float(attr_p[min(i + (lane >> 4), lim) * 16 + (lane & 15)]);
            float xs[4];
#pragma unroll
            for (int j = 0; j < 4; ++j) {
                int s = __builtin_amdgcn_readlane(sv, j);
                xs[j] = y[s * 64 + lane];
            }
            int ns = end - i;
#pragma unroll
            for (int j = 0; j < 4; ++j) {
                if (j < ns) {
                    float el = ebl;
#pragma unroll
                    for (int k = 0; k < 16; ++k)
                        el = fmaf(bcastf(ea, j * 16 + k), rw[k], el);
                    float xv = fmaxf(fmaf(xs[j], sA, sB), relu_neg);
                    float m  = fmaxf(xv + el, 0.f) + 1e-7f;
                    float e2 = __expf(m);
                    num = fmaf(m, e2, num);
                    den += e2;
                }
            }
        }
        agg[n * 64 + lane] = num / (den + 1e-16f) + xr;
    }
}

// -------------------- t = agg @ w1 + b1 ; accumulate per-channel sum/sumsq ----------
__global__ __launch_bounds__(256) void k_mlp1(const float* __restrict__ agg,
                                              const float* __restrict__ w1,
                                              const float* __restrict__ b1,
                                              float* __restrict__ tbuf,
                                              float* __restrict__ s1) {
    __shared__ float s_w[64 * 128];
    __shared__ float red[256];
    int tid = threadIdx.x;
    for (int i = tid; i < 64 * 128 / 4; i += 256) ((float4*)s_w)[i] = ((const float4*)w1)[i];
    __syncthreads();
    int c = tid & 127, half = tid >> 7;
    float bc = b1[c];
    float lsum = 0.f, lsq = 0.f;
    for (int n = blockIdx.x * 2 + half; n < N_NODES; n += gridDim.x * 2) {
        const float* ar = agg + n * 64;
        float a0 = bc, a1 = 0.f;
#pragma unroll
        for (int k = 0; k < 64; k += 2) {
            a0 = fmaf(ar[k],     s_w[k * 128 + c],       a0);
            a1 = fmaf(ar[k + 1], s_w[(k + 1) * 128 + c], a1);
        }
        float acc = a0 + a1;
        tbuf[n * 128 + c] = acc;
        lsum += acc;
        lsq = fmaf(acc, acc, lsq);
    }
    red[tid] = lsum;
    __syncthreads();
    if (half == 0) atomicAdd(&s1[c], red[c] + red[c + 128]);
    __syncthreads();
    red[tid] = lsq;
    __syncthreads();
    if (half == 0) atomicAdd(&s1[128 + c], red[c] + red[c + 128]);
}

// -------------------- y = relu(bn(t)) @ w2 + b2 ; accumulate y stats ----------------
__global__ __launch_bounds__(256) void k_mlp2(const float* __restrict__ tbuf,
                                              const float* __restrict__ w2,
                                              const float* __restrict__ b2,
                                              const float* __restrict__ s1,
                                              const float* __restrict__ bng,
                                              const float* __restrict__ bnb,
                                              float* __restrict__ ybuf,
                                              float* __restrict__ s2) {
    __shared__ float s_w[128 * 64];
    __shared__ float red[4][64][2];
    int tid = threadIdx.x, lane = tid & 63, w = tid >> 6;
    for (int i = tid; i < 128 * 64 / 4; i += 256) ((float4*)s_w)[i] = ((const float4*)w2)[i];
    float mu0 = s1[lane] * (1.f / N_NODES);
    float v0  = s1[128 + lane] * (1.f / N_NODES) - mu0 * mu0;
    float iA  = rsqrtf(v0 + 1e-5f) * bng[lane];
    float iB  = bnb[lane] - mu0 * iA;
    float mu1 = s1[lane + 64] * (1.f / N_NODES);
    float v1  = s1[128 + lane + 64] * (1.f / N_NODES) - mu1 * mu1;
    float jA  = rsqrtf(v1 + 1e-5f) * bng[lane + 64];
    float jB  = bnb[lane + 64] - mu1 * jA;
    float b2c = b2[lane];
    float lsum = 0.f, lsq = 0.f;
    __syncthreads();
    for (int n = blockIdx.x * 4 + w; n < N_NODES; n += gridDim.x * 4) {
        float t0 = tbuf[n * 128 + lane];
        float t1 = tbuf[n * 128 + 64 + lane];
        float h0 = fmaxf(fmaf(t0, iA, iB), 0.f);
        float h1 = fmaxf(fmaf(t1, jA, jB), 0.f);
        float a0 = b2c, a1 = 0.f, a2 = 0.f, a3 = 0.f;
#pragma unroll
        for (int k = 0; k < 64; k += 2) {
            a0 = fmaf(__shfl(h0, k,     64), s_w[k * 64 + lane],        a0);
            a1 = fmaf(__shfl(h0, k + 1, 64), s_w[(k + 1) * 64 + lane],  a1);
            a2 = fmaf(__shfl(h1, k,     64), s_w[(k + 64) * 64 + lane], a2);
            a3 = fmaf(__shfl(h1, k + 1, 64), s_w[(k + 65) * 64 + lane], a3);
        }
        float acc = (a0 + a1) + (a2 + a3);
        ybuf[n * 64 + lane] = acc;
        lsum += acc;
        lsq = fmaf(acc, acc, lsq);
    }
    red[w][lane][0] = lsum;
    red[w][lane][1] = lsq;
    __syncthreads();
    if (w == 0) {
        float s = red[0][lane][0] + red[1][lane][0] + red[2][lane][0] + red[3][lane][0];
        float q = red[0][lane][1] + red[1][lane][1] + red[2][lane][1] + red[3][lane][1];
        atomicAdd(&s2[lane], s);
        atomicAdd(&s2[64 + lane], q);
    }
}

// -------------------- final outer BN (no relu), float4 --------------------
__global__ __launch_bounds__(256) void k_bn2(const float* __restrict__ y,
                                             const float* __restrict__ s2,
                                             const float* __restrict__ g,
                                             const float* __restrict__ b,
                                             float* __restrict__ xout) {
    int idx = blockIdx.x * blockDim.x + threadIdx.x;   // N*16 float4s
    if (idx >= N_NODES * 16) return;
    int c0 = (idx & 15) * 4;
    float4 v = ((const float4*)y)[idx];
    float* vp = &v.x;
    float out[4];
#pragma unroll
    for (int j = 0; j < 4; ++j) {
        int c = c0 + j;
        float mu  = s2[c] * (1.f / N_NODES);
        float var = s2[64 + c] * (1.f / N_NODES) - mu * mu;
        float inv = rsqrtf(var + 1e-5f);
        out[j] = (vp[j] - mu) * inv * g[c] + b[c];
    }
    ((float4*)xout)[idx] = make_float4(out[0], out[1], out[2], out[3]);
}

extern "C" void kernel_launch(void* const* d_in, const int* in_sizes, int n_in,
                              void* d_out, int out_size, void* d_ws, size_t ws_size,
                              hipStream_t stream) {
    const float* z     = (const float*)d_in[0];
    const int*   batch = (const int*)  d_in[1];
    const int*   eidx  = (const int*)  d_in[2];
    const float* eattr = (const float*)d_in[3];
    const float* lin_w = (const float*)d_in[4];
    const float* lin_b = (const float*)d_in[5];
    const int* src = eidx;
    const int* dst = eidx + N_EDGES;

    char* ws = (char*)d_ws;
    size_t off = 0;
    auto alloc = [&](size_t bytes) -> void* {
        void* p = ws + off;
        off = (off + bytes + 255) & ~(size_t)255;
        return p;
    };
    float*  p        = (float*) alloc((size_t)B_GRAPH * HID * 4);
    float*  bufA     = (float*) alloc((size_t)N_NODES * 64 * 4);   // latent gather / ping
    float*  bufB     = (float*) alloc((size_t)N_NODES * 64 * 4);   // pong
    float*  agg      = (float*) alloc((size_t)N_NODES * 64 * 4);
    float*  tbuf     = (float*) alloc((size_t)N_NODES * 128 * 4);
    int*    rowstart = (int*)   alloc((size_t)(N_NODES + 1) * 4);
    int*    cursor   = (int*)   alloc((size_t)(N_NODES + 1) * 4);  // doubles as counts
    int*    btot     = (int*)   alloc(64 * 4);
    int*    boff     = (int*)   alloc(65 * 4);
    int*    csr_src  = (int*)   alloc((size_t)N_EDGES * 4);
    int*    csr_eid  = (int*)   alloc((size_t)N_EDGES * 4);
    __half* attr_p   = (__half*)alloc((size_t)N_EDGES * 16 * 2);
    float*  stats    = (float*) alloc((size_t)3 * 384 * 4);

    hipMemsetAsync(cursor, 0, (size_t)(N_NODES + 1) * 4, stream);
    hipMemsetAsync(stats,  0, (size_t)3 * 384 * 4, stream);

    k_linz   <<<(B_GRAPH * HID + 255) / 256, 256, 0, stream>>>(z, lin_w, lin_b, p);
    k_gather <<<(N_NODES * 16 + 255) / 256, 256, 0, stream>>>(p, batch, bufA);
    k_count  <<<(N_EDGES + 255) / 256, 256, 0, stream>>>(dst, cursor);
    k_scanA  <<<NBLK_SCAN, 1024, 0, stream>>>(cursor, rowstart, btot);
    k_scanB  <<<1, 64, 0, stream>>>(btot, boff);
    k_scanC  <<<(N_NODES + 256) / 256, 256, 0, stream>>>(rowstart, boff, cursor);
    k_scatter<<<(N_EDGES + 255) / 256, 256, 0, stream>>>(src, dst, cursor, csr_src, csr_eid);
    k_permute<<<(N_EDGES * 16 + 255) / 256, 256, 0, stream>>>(eattr, csr_eid, attr_p);

    const float* IN[3]  = { bufA, bufB, bufA };
    float*       OUT[3] = { bufB, bufA, bufB };
    for (int l = 0; l < 3; ++l) {
        const float* ew  = (const float*)d_in[6 + l * 10 + 0];
        const float* eb  = (const float*)d_in[6 + l * 10 + 1];
        const float* w1  = (const float*)d_in[6 + l * 10 + 2];
        const float* b1  = (const float*)d_in[6 + l * 10 + 3];
        const float* bng = (const float*)d_in[6 + l * 10 + 4];
        const float* bnb = (const float*)d_in[6 + l * 10 + 5];
        const float* w2  = (const float*)d_in[6 + l * 10 + 6];
        const float* b2  = (const float*)d_in[6 + l * 10 + 7];
        float* s1 = stats + l * 384;
        float* s2 = s1 + 256;
        const float* prev_s2 = (l == 0) ? nullptr : stats + (l - 1) * 384 + 256;
        const float* prev_g  = (l == 0) ? nullptr : (const float*)d_in[6 + (l - 1) * 10 + 8];
        const float* prev_b  = (l == 0) ? nullptr : (const float*)d_in[6 + (l - 1) * 10 + 9];
        float relu_neg = (l == 0) ? -1e30f : 0.f;

        k_edge<<<2048, 256, 0, stream>>>(IN[l], prev_s2, prev_g, prev_b, relu_neg,
                                         rowstart, csr_src, attr_p, ew, eb, agg);
        k_mlp1<<<512, 256, 0, stream>>>(agg, w1, b1, tbuf, s1);
        k_mlp2<<<512, 256, 0, stream>>>(tbuf, w2, b2, s1, bng, bnb, OUT[l], s2);
    }
    // final: bn(conv3_out; n3), no relu
    k_bn2<<<(N_NODES * 16 + 255) / 256, 256, 0, stream>>>(bufB, stats + 2 * 384 + 256,
                                                          (const float*)d_in[6 + 2 * 10 + 8],
                                                          (const float*)d_in[6 + 2 * 10 + 9],
                                                          (float*)d_out);
}

// Round 4
// 718.138 us; speedup vs baseline: 1.6871x; 1.1248x over previous
//
#include <hip/hip_runtime.h>
#include <hip/hip_fp16.h>

#define N_NODES 50000
#define N_EDGES 800000
#define B_GRAPH 256
#define IN_DIM  128
#define HID     64
#define NBLK_SCAN ((N_NODES + 1023) / 1024)   // 49

// -------------------- initial latent: p = relu(z @ lin_w + lin_b) --------------------
__global__ __launch_bounds__(256) void k_linz(const float* __restrict__ z,
                                              const float* __restrict__ w,
                                              const float* __restrict__ b,
                                              float* __restrict__ p) {
    int idx = blockIdx.x * blockDim.x + threadIdx.x;
    if (idx >= B_GRAPH * HID) return;
    int row = idx >> 6, c = idx & 63;
    float acc = b[c];
    const float* zr = z + row * IN_DIM;
#pragma unroll 8
    for (int k = 0; k < IN_DIM; ++k) acc = fmaf(zr[k], w[k * HID + c], acc);
    p[idx] = fmaxf(acc, 0.f);
}

// -------------------- x0[n] = p[batch[n]] (float4) --------------------
__global__ __launch_bounds__(256) void k_gather(const float* __restrict__ p,
                                                const int* __restrict__ batch,
                                                float* __restrict__ x0) {
    int idx = blockIdx.x * blockDim.x + threadIdx.x;
    if (idx >= N_NODES * 16) return;
    int n = idx >> 4, q = idx & 15;
    ((float4*)x0)[idx] = ((const float4*)(p + batch[n] * 64))[q];
}

// -------------------- CSR build --------------------
__global__ __launch_bounds__(256) void k_count(const int* __restrict__ dst,
                                               int* __restrict__ counts) {
    int e = blockIdx.x * blockDim.x + threadIdx.x;
    if (e < N_EDGES) atomicAdd(&counts[dst[e]], 1);
}

__global__ __launch_bounds__(1024) void k_scanA(const int* __restrict__ counts,
                                                int* __restrict__ rowstart,
                                                int* __restrict__ btot) {
    __shared__ int wsum[16];
    int tid = threadIdx.x, lane = tid & 63, w = tid >> 6;
    int i = blockIdx.x * 1024 + tid;
    int v = (i < N_NODES) ? counts[i] : 0;
    int s = v;
#pragma unroll
    for (int off = 1; off < 64; off <<= 1) {
        int t = __shfl_up(s, off, 64);
        if (lane >= off) s += t;
    }
    if (lane == 63) wsum[w] = s;
    __syncthreads();
    if (w == 0) {
        int ws = (lane < 16) ? wsum[lane] : 0;
#pragma unroll
        for (int off = 1; off < 16; off <<= 1) {
            int t = __shfl_up(ws, off, 64);
            if (lane >= off) ws += t;
        }
        if (lane < 16) wsum[lane] = ws;
    }
    __syncthreads();
    int wbase = (w == 0) ? 0 : wsum[w - 1];
    if (i < N_NODES) rowstart[i] = wbase + s - v;
    if (tid == 0) btot[blockIdx.x] = wsum[15];
}

__global__ __launch_bounds__(64) void k_scanB(const int* __restrict__ btot,
                                              int* __restrict__ boff) {
    int lane = threadIdx.x;
    int v = (lane < NBLK_SCAN) ? btot[lane] : 0;
    int s = v;
#pragma unroll
    for (int off = 1; off < 64; off <<= 1) {
        int t = __shfl_up(s, off, 64);
        if (lane >= off) s += t;
    }
    if (lane < NBLK_SCAN) boff[lane] = s - v;
    if (lane == 63) boff[NBLK_SCAN] = s;
}

__global__ __launch_bounds__(256) void k_scanC(int* __restrict__ rowstart,
                                               const int* __restrict__ boff,
                                               int* __restrict__ cursor) {
    int i = blockIdx.x * blockDim.x + threadIdx.x;
    if (i < N_NODES) {
        int r = rowstart[i] + boff[i >> 10];
        rowstart[i] = r;
        cursor[i] = r;
    } else if (i == N_NODES) {
        rowstart[N_NODES] = boff[NBLK_SCAN];
    }
}

// -------------------- scatter: CSR src + packed fp16 attr in one pass --------------------
__global__ __launch_bounds__(256) void k_scatter(const int* __restrict__ src,
                                                 const int* __restrict__ dst,
                                                 const float* __restrict__ ea,
                                                 int* __restrict__ cursor,
                                                 int* __restrict__ csr_src,
                                                 __half2* __restrict__ attr_h) {
    int e = blockIdx.x * blockDim.x + threadIdx.x;
    if (e >= N_EDGES) return;
    int d = dst[e];
    int pos = atomicAdd(&cursor[d], 1);
    csr_src[pos] = src[e];
    const float4* s0 = (const float4*)(ea + (size_t)e * 16);
    float4 f0 = s0[0], f1 = s0[1], f2 = s0[2], f3 = s0[3];
    uint4 u0, u1;
    u0.x = __builtin_bit_cast(unsigned, __floats2half2_rn(f0.x, f0.y));
    u0.y = __builtin_bit_cast(unsigned, __floats2half2_rn(f0.z, f0.w));
    u0.z = __builtin_bit_cast(unsigned, __floats2half2_rn(f1.x, f1.y));
    u0.w = __builtin_bit_cast(unsigned, __floats2half2_rn(f1.z, f1.w));
    u1.x = __builtin_bit_cast(unsigned, __floats2half2_rn(f2.x, f2.y));
    u1.y = __builtin_bit_cast(unsigned, __floats2half2_rn(f2.z, f2.w));
    u1.z = __builtin_bit_cast(unsigned, __floats2half2_rn(f3.x, f3.y));
    u1.w = __builtin_bit_cast(unsigned, __floats2half2_rn(f3.z, f3.w));
    uint4* op = (uint4*)(attr_h + (size_t)pos * 8);
    op[0] = u0;
    op[1] = u1;
}

// -------------------- edge pass: one wave per node, lane = channel --------------------
// attr via wave-uniform loads (no readlane); edge-linear as 8x __hfma2.
__global__ __launch_bounds__(256) void k_edge(const float* __restrict__ y,
                                              const float* __restrict__ s2,
                                              const float* __restrict__ bg,
                                              const float* __restrict__ bb,
                                              float relu_neg,
                                              const int* __restrict__ rowstart,
                                              const int* __restrict__ csr_src,
                                              const __half2* __restrict__ attr_h,
                                              const float* __restrict__ ew,
                                              const float* __restrict__ eb,
                                              float* __restrict__ agg) {
    int tid = threadIdx.x, lane = tid & 63;
    __half2 rw2[8];
#pragma unroll
    for (int k = 0; k < 8; ++k)
        rw2[k] = __floats2half2_rn(ew[(2 * k) * 64 + lane], ew[(2 * k + 1) * 64 + lane]);
    float ebl = eb[lane];
    float sA = 1.f, sB = 0.f;
    if (s2) {
        float mu  = s2[lane] * (1.f / N_NODES);
        float var = s2[64 + lane] * (1.f / N_NODES) - mu * mu;
        sA = rsqrtf(var + 1e-5f) * bg[lane];
        sB = bb[lane] - mu * sA;
    }
    const __half2 hz = __float2half2_rn(0.f);
    int wave = blockIdx.x * 4 + (tid >> 6);
    int nw = gridDim.x * 4;
    for (int n0 = wave; n0 < N_NODES; n0 += nw) {
        int n = __builtin_amdgcn_readfirstlane(n0);
        int beg = rowstart[n], end = rowstart[n + 1];
        float xr = fmaxf(fmaf(y[(size_t)n * 64 + lane], sA, sB), relu_neg);
        float num = 0.f, den = 0.f;
        for (int i = beg; i < end; i += 4) {
            int lim = end - 1;
            int sv = csr_src[min(i + (lane & 3), lim)];
            float xs[4];
            uint4 ua[4], ub[4];
#pragma unroll
            for (int j = 0; j < 4; ++j) {
                int s = __builtin_amdgcn_readlane(sv, j);
                xs[j] = y[(size_t)s * 64 + lane];
                int ej = min(i + j, lim);               // wave-uniform
                const uint4* ap = (const uint4*)(attr_h + (size_t)ej * 8);
                ua[j] = ap[0];
                ub[j] = ap[1];
            }
            int ns = end - i;
#pragma unroll
            for (int j = 0; j < 4; ++j) {
                if (j < ns) {
                    __half2 aE = hz, aO = hz;
                    aE = __hfma2(__builtin_bit_cast(__half2, ua[j].x), rw2[0], aE);
                    aO = __hfma2(__builtin_bit_cast(__half2, ua[j].y), rw2[1], aO);
                    aE = __hfma2(__builtin_bit_cast(__half2, ua[j].z), rw2[2], aE);
                    aO = __hfma2(__builtin_bit_cast(__half2, ua[j].w), rw2[3], aO);
                    aE = __hfma2(__builtin_bit_cast(__half2, ub[j].x), rw2[4], aE);
                    aO = __hfma2(__builtin_bit_cast(__half2, ub[j].y), rw2[5], aO);
                    aE = __hfma2(__builtin_bit_cast(__half2, ub[j].z), rw2[6], aE);
                    aO = __hfma2(__builtin_bit_cast(__half2, ub[j].w), rw2[7], aO);
                    float el = ebl + (__low2float(aE) + __high2float(aE))
                                   + (__low2float(aO) + __high2float(aO));
                    float xv = fmaxf(fmaf(xs[j], sA, sB), relu_neg);
                    float m  = fmaxf(xv + el, 0.f) + 1e-7f;
                    float e2 = __expf(m);
                    num = fmaf(m, e2, num);
                    den += e2;
                }
            }
        }
        agg[(size_t)n * 64 + lane] = num / (den + 1e-16f) + xr;
    }
}

// -------------------- t = agg @ w1 + b1 ; stats. lane holds w1[:, lane] & w1[:, lane+64] ----
__global__ __launch_bounds__(256, 1) void k_mlp1(const float* __restrict__ agg,
                                                 const float* __restrict__ w1,
                                                 const float* __restrict__ b1,
                                                 float* __restrict__ tbuf,
                                                 float* __restrict__ s1) {
    int tid = threadIdx.x, lane = tid & 63;
    float wA[64], wB[64];
#pragma unroll
    for (int k = 0; k < 64; ++k) {
        wA[k] = w1[k * 128 + lane];
        wB[k] = w1[k * 128 + 64 + lane];
    }
    float bA = b1[lane], bB = b1[64 + lane];
    float sumA = 0.f, sumB = 0.f, sqA = 0.f, sqB = 0.f;
    int wave = blockIdx.x * 4 + (tid >> 6);
    int nw = gridDim.x * 4;
    for (int n0 = wave; n0 < N_NODES; n0 += nw) {
        int n = __builtin_amdgcn_readfirstlane(n0);
        const float4* ar = (const float4*)(agg + (size_t)n * 64);
        float accA = bA, accB = bB;
#pragma unroll
        for (int q = 0; q < 16; ++q) {
            float4 r = ar[q];
            accA = fmaf(r.x, wA[4 * q],     accA); accB = fmaf(r.x, wB[4 * q],     accB);
            accA = fmaf(r.y, wA[4 * q + 1], accA); accB = fmaf(r.y, wB[4 * q + 1], accB);
            accA = fmaf(r.z, wA[4 * q + 2], accA); accB = fmaf(r.z, wB[4 * q + 2], accB);
            accA = fmaf(r.w, wA[4 * q + 3], accA); accB = fmaf(r.w, wB[4 * q + 3], accB);
        }
        tbuf[(size_t)n * 128 + lane] = accA;
        tbuf[(size_t)n * 128 + 64 + lane] = accB;
        sumA += accA; sqA = fmaf(accA, accA, sqA);
        sumB += accB; sqB = fmaf(accB, accB, sqB);
    }
    atomicAdd(&s1[lane], sumA);
    atomicAdd(&s1[64 + lane], sumB);
    atomicAdd(&s1[128 + lane], sqA);
    atomicAdd(&s1[192 + lane], sqB);
}

// -------------------- tbuf = relu(bn(tbuf)) in-place, float4 --------------------
__global__ __launch_bounds__(256) void k_bnrelu(float* __restrict__ tbuf,
                                                const float* __restrict__ s1,
                                                const float* __restrict__ bng,
                                                const float* __restrict__ bnb) {
    int idx = blockIdx.x * blockDim.x + threadIdx.x;   // N*32 float4s
    if (idx >= N_NODES * 32) return;
    int c0 = (idx & 31) * 4;
    float4 v = ((const float4*)tbuf)[idx];
    float* vp = &v.x;
#pragma unroll
    for (int j = 0; j < 4; ++j) {
        int c = c0 + j;
        float mu  = s1[c] * (1.f / N_NODES);
        float var = s1[128 + c] * (1.f / N_NODES) - mu * mu;
        float a   = rsqrtf(var + 1e-5f) * bng[c];
        vp[j] = fmaxf(fmaf(vp[j], a, bnb[c] - mu * a), 0.f);
    }
    ((float4*)tbuf)[idx] = v;
}

// -------------------- y = h @ w2 + b2 ; stats. lane holds w2[:, lane] (128 regs) ----
__global__ __launch_bounds__(256, 1) void k_mlp2(const float* __restrict__ h,
                                                 const float* __restrict__ w2,
                                                 const float* __restrict__ b2,
                                                 float* __restrict__ ybuf,
                                                 float* __restrict__ s2) {
    int tid = threadIdx.x, lane = tid & 63;
    float wv[128];
#pragma unroll
    for (int k = 0; k < 128; ++k) wv[k] = w2[k * 64 + lane];
    float bc = b2[lane];
    float lsum = 0.f, lsq = 0.f;
    int wave = blockIdx.x * 4 + (tid >> 6);
    int nw = gridDim.x * 4;
    for (int n0 = wave; n0 < N_NODES; n0 += nw) {
        int n = __builtin_amdgcn_readfirstlane(n0);
        const float4* hr = (const float4*)(h + (size_t)n * 128);
        float a0 = bc, a1 = 0.f;
#pragma unroll
        for (int q = 0; q < 32; ++q) {
            float4 r = hr[q];
            a0 = fmaf(r.x, wv[4 * q],     a0);
            a1 = fmaf(r.y, wv[4 * q + 1], a1);
            a0 = fmaf(r.z, wv[4 * q + 2], a0);
            a1 = fmaf(r.w, wv[4 * q + 3], a1);
        }
        float acc = a0 + a1;
        ybuf[(size_t)n * 64 + lane] = acc;
        lsum += acc;
        lsq = fmaf(acc, acc, lsq);
    }
    atomicAdd(&s2[lane], lsum);
    atomicAdd(&s2[64 + lane], lsq);
}

// -------------------- final outer BN (no relu), float4 --------------------
__global__ __launch_bounds__(256) void k_bn2(const float* __restrict__ y,
                                             const float* __restrict__ s2,
                                             const float* __restrict__ g,
                                             const float* __restrict__ b,
                                             float* __restrict__ xout) {
    int idx = blockIdx.x * blockDim.x + threadIdx.x;   // N*16 float4s
    if (idx >= N_NODES * 16) return;
    int c0 = (idx & 15) * 4;
    float4 v = ((const float4*)y)[idx];
    float* vp = &v.x;
    float out[4];
#pragma unroll
    for (int j = 0; j < 4; ++j) {
        int c = c0 + j;
        float mu  = s2[c] * (1.f / N_NODES);
        float var = s2[64 + c] * (1.f / N_NODES) - mu * mu;
        float inv = rsqrtf(var + 1e-5f);
        out[j] = (vp[j] - mu) * inv * g[c] + b[c];
    }
    ((float4*)xout)[idx] = make_float4(out[0], out[1], out[2], out[3]);
}

extern "C" void kernel_launch(void* const* d_in, const int* in_sizes, int n_in,
                              void* d_out, int out_size, void* d_ws, size_t ws_size,
                              hipStream_t stream) {
    const float* z     = (const float*)d_in[0];
    const int*   batch = (const int*)  d_in[1];
    const int*   eidx  = (const int*)  d_in[2];
    const float* eattr = (const float*)d_in[3];
    const float* lin_w = (const float*)d_in[4];
    const float* lin_b = (const float*)d_in[5];
    const int* src = eidx;
    const int* dst = eidx + N_EDGES;

    char* ws = (char*)d_ws;
    size_t off = 0;
    auto alloc = [&](size_t bytes) -> void* {
        void* p = ws + off;
        off = (off + bytes + 255) & ~(size_t)255;
        return p;
    };
    float*   p        = (float*)  alloc((size_t)B_GRAPH * HID * 4);
    float*   bufA     = (float*)  alloc((size_t)N_NODES * 64 * 4);
    float*   bufB     = (float*)  alloc((size_t)N_NODES * 64 * 4);
    float*   agg      = (float*)  alloc((size_t)N_NODES * 64 * 4);
    float*   tbuf     = (float*)  alloc((size_t)N_NODES * 128 * 4);
    int*     rowstart = (int*)    alloc((size_t)(N_NODES + 1) * 4);
    int*     cursor   = (int*)    alloc((size_t)(N_NODES + 1) * 4);
    int*     btot     = (int*)    alloc(64 * 4);
    int*     boff     = (int*)    alloc(65 * 4);
    int*     csr_src  = (int*)    alloc((size_t)N_EDGES * 4);
    __half2* attr_h   = (__half2*)alloc((size_t)N_EDGES * 16 * 2);
    float*   stats    = (float*)  alloc((size_t)3 * 512 * 4);

    hipMemsetAsync(cursor, 0, (size_t)(N_NODES + 1) * 4, stream);
    hipMemsetAsync(stats,  0, (size_t)3 * 512 * 4, stream);

    k_linz   <<<(B_GRAPH * HID + 255) / 256, 256, 0, stream>>>(z, lin_w, lin_b, p);
    k_gather <<<(N_NODES * 16 + 255) / 256, 256, 0, stream>>>(p, batch, bufA);
    k_count  <<<(N_EDGES + 255) / 256, 256, 0, stream>>>(dst, cursor);
    k_scanA  <<<NBLK_SCAN, 1024, 0, stream>>>(cursor, rowstart, btot);
    k_scanB  <<<1, 64, 0, stream>>>(btot, boff);
    k_scanC  <<<(N_NODES + 256) / 256, 256, 0, stream>>>(rowstart, boff, cursor);
    k_scatter<<<(N_EDGES + 255) / 256, 256, 0, stream>>>(src, dst, eattr, cursor, csr_src, attr_h);

    const float* IN[3]  = { bufA, bufB, bufA };
    float*       OUT[3] = { bufB, bufA, bufB };
    for (int l = 0; l < 3; ++l) {
        const float* ew  = (const float*)d_in[6 + l * 10 + 0];
        const float* eb  = (const float*)d_in[6 + l * 10 + 1];
        const float* w1  = (const float*)d_in[6 + l * 10 + 2];
        const float* b1  = (const float*)d_in[6 + l * 10 + 3];
        const float* bng = (const float*)d_in[6 + l * 10 + 4];
        const float* bnb = (const float*)d_in[6 + l * 10 + 5];
        const float* w2  = (const float*)d_in[6 + l * 10 + 6];
        const float* b2  = (const float*)d_in[6 + l * 10 + 7];
        float* s1 = stats + l * 512;
        float* s2 = s1 + 384;
        const float* prev_s2 = (l == 0) ? nullptr : stats + (l - 1) * 512 + 384;
        const float* prev_g  = (l == 0) ? nullptr : (const float*)d_in[6 + (l - 1) * 10 + 8];
        const float* prev_b  = (l == 0) ? nullptr : (const float*)d_in[6 + (l - 1) * 10 + 9];
        float relu_neg = (l == 0) ? -1e30f : 0.f;

        k_edge  <<<2048, 256, 0, stream>>>(IN[l], prev_s2, prev_g, prev_b, relu_neg,
                                           rowstart, csr_src, attr_h, ew, eb, agg);
        k_mlp1  <<<512, 256, 0, stream>>>(agg, w1, b1, tbuf, s1);
        k_bnrelu<<<(N_NODES * 32 + 255) / 256, 256, 0, stream>>>(tbuf, s1, bng, bnb);
        k_mlp2  <<<512, 256, 0, stream>>>(tbuf, w2, b2, OUT[l], s2);
    }
    k_bn2<<<(N_NODES * 16 + 255) / 256, 256, 0, stream>>>(bufB, stats + 2 * 512 + 384,
                                                          (const float*)d_in[6 + 2 * 10 + 8],
                                                          (const float*)d_in[6 + 2 * 10 + 9],
                                                          (float*)d_out);
}